// Round 20
// baseline (312.512 us; speedup 1.0000x reference)
//
#include <hip/hip_runtime.h>

// R20: R17's 2-phase pipeline with V moved OUT of LDS: V fragments loaded
// per-wave direct from ws (L2-resident via XCD-affine queues) into 32
// short-lived VGPRs, issued at TOP of each step (full-softmax flight).
// LDS = K double-buffer only (16.6KB) -> __launch_bounds__(128,3) ->
// 6 blocks/CU, 3 waves/SIMD (1.5x TLP). Counted vmcnt(4) keeps K(t+2)
// glds in flight across barrier1. Math/prep/queues identical.

#define BB 4
#define QQ 1024
#define SS 2048
#define HH 32
#define DD 128
#define KT 32
#define NTILES 64
#define TILE_ELEMS 4096
#define NPERQ 256

typedef __attribute__((ext_vector_type(8))) short short8;
typedef __attribute__((ext_vector_type(4))) float f32x4;
typedef __attribute__((ext_vector_type(16))) float f32x16;
typedef __attribute__((ext_vector_type(4))) unsigned int u32x4;
typedef __attribute__((ext_vector_type(8))) unsigned short u16x8;

__device__ __forceinline__ unsigned short f2bf(float f) {
    unsigned int u = __builtin_bit_cast(unsigned int, f);
    u += 0x7FFFu + ((u >> 16) & 1u);
    return (unsigned short)(u >> 16);
}
__device__ __forceinline__ unsigned int cvtpk(float lo, float hi) {
    unsigned int r;
    asm("v_cvt_pk_bf16_f32 %0, %1, %2" : "=v"(r) : "v"(lo), "v"(hi));
    return r;
}
__device__ __forceinline__ void glds16(const unsigned short* g, unsigned short* l) {
    __builtin_amdgcn_global_load_lds(
        (const __attribute__((address_space(1))) unsigned int*)g,
        (__attribute__((address_space(3))) unsigned int*)l, 16, 0, 0);
}

// ---------------- prep: f32 cache/new -> bf16 32x32-fragment-ordered ws -------
__global__ __launch_bounds__(256)
void prep(const float* __restrict__ ks, const float* __restrict__ vs,
          const float* __restrict__ kc_, const float* __restrict__ vc,
          const int* __restrict__ qlens, const int* __restrict__ clens,
          unsigned short* __restrict__ Kws, unsigned short* __restrict__ Vws)
{
    const int tile = blockIdx.x, h = blockIdx.y, b = blockIdx.z;
    const int qlen = qlens[b], clen = clens[b];
    if (tile * KT >= clen + qlen) return;
    const int tid = threadIdx.x;
    unsigned short* kout = Kws + (((size_t)b * HH + h) * NTILES + tile) * TILE_ELEMS;
    unsigned short* vout = Vws + (((size_t)b * HH + h) * NTILES + tile) * TILE_ELEMS;

    #pragma unroll
    for (int h2 = 0; h2 < 2; ++h2) {
        const int idx8 = h2 * 2048 + tid * 8;
        const int c = idx8 >> 9, l = (idx8 >> 3) & 63;
        int key = tile * KT + (l & 31);
        const float* src;
        if (key < clen) {
            src = kc_ + (((size_t)b * SS + key) * HH + h) * DD;
        } else {
            int i2 = key - clen; if (i2 > QQ - 1) i2 = QQ - 1;
            src = ks + (((size_t)b * QQ + i2) * HH + h) * DD;
        }
        const int d0 = c * 16 + ((l >> 5) << 3);
        f32x4 a0 = *(const f32x4*)&src[d0];
        f32x4 a1 = *(const f32x4*)&src[d0 + 4];
        u16x8 w;
        w[0] = f2bf(a0[0]); w[1] = f2bf(a0[1]); w[2] = f2bf(a0[2]); w[3] = f2bf(a0[3]);
        w[4] = f2bf(a1[0]); w[5] = f2bf(a1[1]); w[6] = f2bf(a1[2]); w[7] = f2bf(a1[3]);
        *(u16x8*)&kout[idx8] = w;
    }
    #pragma unroll
    for (int h2 = 0; h2 < 2; ++h2) {
        const int idx8 = h2 * 2048 + tid * 8;
        const int a = idx8 >> 9, l = (idx8 >> 3) & 63;
        const int dchunk = a >> 1, kcc = a & 1;
        const int d = dchunk * 32 + (l & 31);
        const int kb = tile * KT + kcc * 16 + ((l >> 5) << 3);
        u16x8 w;
        #pragma unroll
        for (int e = 0; e < 8; ++e) {
            int key = kb + e;
            const float* src;
            if (key < clen) {
                src = vc + (((size_t)b * SS + key) * HH + h) * DD;
            } else {
                int i2 = key - clen; if (i2 > QQ - 1) i2 = QQ - 1;
                src = vs + (((size_t)b * QQ + i2) * HH + h) * DD;
            }
            w[e] = f2bf(src[d]);
        }
        *(u16x8*)&vout[idx8] = w;
    }
}

// ---- one pipelined step:
// load vf(T) direct (8x dwordx4); issue K(T+2) glds -> Kl[BC] (dead);
// softmax(T); vmcnt(4)+barrier; QK(T+1) from Kl[BN] + PV(T) from vf;
// lgkm+barrier.
#define TSTEP(T, SC, SN, BC, BN)                                                \
{                                                                               \
    const int pbase = (T) * KT;                                                 \
    const unsigned short* vtp = Vb + (size_t)(T) * TILE_ELEMS;                  \
    short8 vf0 = *(const short8*)&vtp[0 * 512 + lane * 8];                      \
    short8 vf1 = *(const short8*)&vtp[1 * 512 + lane * 8];                      \
    short8 vf2 = *(const short8*)&vtp[2 * 512 + lane * 8];                      \
    short8 vf3 = *(const short8*)&vtp[3 * 512 + lane * 8];                      \
    short8 vf4 = *(const short8*)&vtp[4 * 512 + lane * 8];                      \
    short8 vf5 = *(const short8*)&vtp[5 * 512 + lane * 8];                      \
    short8 vf6 = *(const short8*)&vtp[6 * 512 + lane * 8];                      \
    short8 vf7 = *(const short8*)&vtp[7 * 512 + lane * 8];                      \
    const int t2c = ((T) + 2 < nt) ? (T) + 2 : (nt - 1);                        \
    const unsigned short* k2p = Kb + (size_t)t2c * TILE_ELEMS;                  \
    _Pragma("unroll")                                                           \
    for (int j = 0; j < 4; ++j)                                                 \
        glds16(&k2p[sbase + j * 512], &Kl[BC][lbase + j * 512]);                \
    if (pbase + KT > lim_min) {                                                 \
        _Pragma("unroll")                                                       \
        for (int r = 0; r < 16; ++r) {                                          \
            const int kk = pbase + (r & 3) + ((r >> 2) << 3) + hi * 4;          \
            if (kk >= lim_l) SC[r] = -3e38f;                                    \
        }                                                                       \
    }                                                                           \
    float pm = fmaxf(fmaxf(fmaxf(fmaxf(SC[0], SC[1]), fmaxf(SC[2], SC[3])),     \
                           fmaxf(fmaxf(SC[4], SC[5]), fmaxf(SC[6], SC[7]))),    \
                     fmaxf(fmaxf(fmaxf(SC[8], SC[9]), fmaxf(SC[10], SC[11])),   \
                           fmaxf(fmaxf(SC[12], SC[13]), fmaxf(SC[14], SC[15])))); \
    if (__any(pm > m_ + 8.0f)) {                                                \
        pm = fmaxf(pm, __shfl_xor(pm, 32));                                     \
        const float mn = fmaxf(m_, pm);                                         \
        const float alpha = __builtin_amdgcn_exp2f(m_ - mn);                    \
        m_ = mn;                                                                \
        l_ *= alpha;                                                            \
        _Pragma("unroll")                                                       \
        for (int r = 0; r < 16; ++r) {                                          \
            o0[r] *= alpha; o1[r] *= alpha; o2[r] *= alpha; o3[r] *= alpha;     \
        }                                                                       \
    }                                                                           \
    float p[16];                                                                \
    _Pragma("unroll")                                                           \
    for (int r = 0; r < 16; ++r) p[r] = __builtin_amdgcn_exp2f(SC[r] - m_);     \
    l_ += (((p[0]+p[1])+(p[2]+p[3])) + ((p[4]+p[5])+(p[6]+p[7])))               \
        + (((p[8]+p[9])+(p[10]+p[11])) + ((p[12]+p[13])+(p[14]+p[15])));        \
    const unsigned int w0 = cvtpk(p[0],  p[1]);                                 \
    const unsigned int w1 = cvtpk(p[2],  p[3]);                                 \
    const unsigned int w2 = cvtpk(p[4],  p[5]);                                 \
    const unsigned int w3 = cvtpk(p[6],  p[7]);                                 \
    const unsigned int w4 = cvtpk(p[8],  p[9]);                                 \
    const unsigned int w5 = cvtpk(p[10], p[11]);                                \
    const unsigned int w6 = cvtpk(p[12], p[13]);                                \
    const unsigned int w7 = cvtpk(p[14], p[15]);                                \
    const unsigned int x0 = (unsigned int)__shfl_xor((int)w0, 32);              \
    const unsigned int x1 = (unsigned int)__shfl_xor((int)w1, 32);              \
    const unsigned int x2 = (unsigned int)__shfl_xor((int)w2, 32);              \
    const unsigned int x3 = (unsigned int)__shfl_xor((int)w3, 32);              \
    const unsigned int x4 = (unsigned int)__shfl_xor((int)w4, 32);              \
    const unsigned int x5 = (unsigned int)__shfl_xor((int)w5, 32);              \
    const unsigned int x6 = (unsigned int)__shfl_xor((int)w6, 32);              \
    const unsigned int x7 = (unsigned int)__shfl_xor((int)w7, 32);              \
    u32x4 pb0w, pb1w;                                                           \
    pb0w[0] = hiL ? x2 : w0;  pb0w[1] = hiL ? x3 : w1;                          \
    pb0w[2] = hiL ? w2 : x0;  pb0w[3] = hiL ? w3 : x1;                          \
    pb1w[0] = hiL ? x6 : w4;  pb1w[1] = hiL ? x7 : w5;                          \
    pb1w[2] = hiL ? w6 : x4;  pb1w[3] = hiL ? w7 : x5;                          \
    const short8 pb0 = __builtin_bit_cast(short8, pb0w);                        \
    const short8 pb1 = __builtin_bit_cast(short8, pb1w);                        \
    asm volatile("s_waitcnt vmcnt(4)" ::: "memory");                            \
    __builtin_amdgcn_s_barrier();                                               \
    __builtin_amdgcn_sched_barrier(0);                                          \
    SN = (f32x16){0.f};                                                         \
    __builtin_amdgcn_s_setprio(1);                                              \
    _Pragma("unroll")                                                           \
    for (int c = 0; c < 8; ++c) {                                               \
        short8 kf = *(const short8*)&Kl[BN][c * 512 + lane * 8];                \
        SN = __builtin_amdgcn_mfma_f32_32x32x16_bf16(kf, qf[c], SN, 0, 0, 0);   \
    }                                                                           \
    o0 = __builtin_amdgcn_mfma_f32_32x32x16_bf16(vf0, pb0, o0, 0, 0, 0);        \
    o0 = __builtin_amdgcn_mfma_f32_32x32x16_bf16(vf1, pb1, o0, 0, 0, 0);        \
    o1 = __builtin_amdgcn_mfma_f32_32x32x16_bf16(vf2, pb0, o1, 0, 0, 0);        \
    o1 = __builtin_amdgcn_mfma_f32_32x32x16_bf16(vf3, pb1, o1, 0, 0, 0);        \
    o2 = __builtin_amdgcn_mfma_f32_32x32x16_bf16(vf4, pb0, o2, 0, 0, 0);        \
    o2 = __builtin_amdgcn_mfma_f32_32x32x16_bf16(vf5, pb1, o2, 0, 0, 0);        \
    o3 = __builtin_amdgcn_mfma_f32_32x32x16_bf16(vf6, pb0, o3, 0, 0, 0);        \
    o3 = __builtin_amdgcn_mfma_f32_32x32x16_bf16(vf7, pb1, o3, 0, 0, 0);        \
    __builtin_amdgcn_s_setprio(0);                                              \
    asm volatile("s_waitcnt lgkmcnt(0)" ::: "memory");                          \
    __builtin_amdgcn_s_barrier();                                               \
    __builtin_amdgcn_sched_barrier(0);                                          \
}

// ---------------- hot: K-only LDS dbuf, V direct, 3 waves/SIMD --------------
__global__ __launch_bounds__(128, 3)
void segattn_persist(const float* __restrict__ qs, const int* __restrict__ qlens,
                     const int* __restrict__ clens,
                     const unsigned short* __restrict__ Kws,
                     const unsigned short* __restrict__ Vws,
                     float* __restrict__ out, int* __restrict__ counter)
{
    __shared__ int s_item;
    alignas(16) __shared__ unsigned short Kl[2][4096];   // K double-buffer only

    const int tid = threadIdx.x, w = tid >> 6, lane = tid & 63;
    const int q31 = lane & 31, hi = lane >> 5;
    const bool hiL = (hi != 0);
    const float psc = 0.08838834764831845f * 1.4426950408889634f;
    const int sbase = w * 2048 + lane * 8;   // per-lane global slice offset (hw)
    const int lbase = w * 2048;              // wave-uniform LDS slice base (hw)
    const int cres = blockIdx.x & 7;         // XCD residue queue
    int* myctr = counter + cres;

    for (;;) {
        if (tid == 0) s_item = atomicAdd(myctr, 1);
        __syncthreads();
        const int pop = s_item;
        __syncthreads();
        if (pop >= NPERQ) break;

        const int bhi = pop >> 4, qtord = pop & 15;
        const int qt = 15 - qtord;
        const int b = bhi & 3, h = cres + 8 * (bhi >> 2);
        const int qlen = qlens[b], clen = clens[b];
        const int q0 = qt * 64;

        if (q0 >= qlen) {                    // fully padded tile -> zeros
            f32x4 z = {0.f, 0.f, 0.f, 0.f};
            #pragma unroll
            for (int i2 = 0; i2 < 16; ++i2) {
                int f = tid + i2 * 128;
                int r = f >> 5, d4 = f & 31;
                *(f32x4*)&out[(((size_t)b * QQ + q0 + r) * HH + h) * DD + d4 * 4] = z;
            }
            continue;
        }

        const int q = q0 + w * 32 + q31;
        const float* qp = qs + (((size_t)b * QQ + q) * HH + h) * DD;
        short8 qf[8];
        #pragma unroll
        for (int c = 0; c < 8; ++c) {
            const int d0 = c * 16 + hi * 8;
            f32x4 a0 = *(const f32x4*)&qp[d0];
            f32x4 a1 = *(const f32x4*)&qp[d0 + 4];
            short8 t;
            t[0] = (short)f2bf(a0[0] * psc); t[1] = (short)f2bf(a0[1] * psc);
            t[2] = (short)f2bf(a0[2] * psc); t[3] = (short)f2bf(a0[3] * psc);
            t[4] = (short)f2bf(a1[0] * psc); t[5] = (short)f2bf(a1[1] * psc);
            t[6] = (short)f2bf(a1[2] * psc); t[7] = (short)f2bf(a1[3] * psc);
            qf[c] = t;
        }

        const int lim_l = (q < qlen) ? (clen + q + 1) : 0;
        const int wq0 = q0 + w * 32;
        const int lim_min = (wq0 + 31 < qlen) ? (clen + wq0 + 1) : 0;

        float m_ = -3e38f, l_ = 0.f;
        f32x16 o0 = {0}, o1 = {0}, o2 = {0}, o3 = {0};

        const int kmax = clen + min(q0 + 64, qlen);
        const int nt = (kmax + KT - 1) / KT;
        const unsigned short* Kb = Kws + ((size_t)(b * HH + h)) * NTILES * TILE_ELEMS;
        const unsigned short* Vb = Vws + ((size_t)(b * HH + h)) * NTILES * TILE_ELEMS;

        // ---- prologue: glds K0 -> buf0; barrier; issue K1 -> buf1; QK(t0); barrier
        #pragma unroll
        for (int j = 0; j < 4; ++j)
            glds16(&Kb[sbase + j * 512], &Kl[0][lbase + j * 512]);
        asm volatile("s_waitcnt vmcnt(0)" ::: "memory");
        __builtin_amdgcn_s_barrier();
        __builtin_amdgcn_sched_barrier(0);
        {
            const int t1x = (nt > 1) ? 1 : 0;
            const unsigned short* k1p = Kb + (size_t)t1x * TILE_ELEMS;
            #pragma unroll
            for (int j = 0; j < 4; ++j)
                glds16(&k1p[sbase + j * 512], &Kl[1][lbase + j * 512]);
        }
        f32x16 sA = {0}, sB;
        __builtin_amdgcn_s_setprio(1);
        #pragma unroll
        for (int c = 0; c < 8; ++c) {
            short8 kf = *(const short8*)&Kl[0][c * 512 + lane * 8];
            sA = __builtin_amdgcn_mfma_f32_32x32x16_bf16(kf, qf[c], sA, 0, 0, 0);
        }
        __builtin_amdgcn_s_setprio(0);
        asm volatile("s_waitcnt lgkmcnt(0)" ::: "memory");
        __builtin_amdgcn_s_barrier();          // buf0.K now block-wide dead
        __builtin_amdgcn_sched_barrier(0);

        int t = 0;
        for (; t + 2 <= nt; t += 2) {
            TSTEP(t,     sA, sB, 0, 1);
            TSTEP(t + 1, sB, sA, 1, 0);
        }
        if (t < nt) {
            TSTEP(t, sA, sB, 0, 1);
        }
        asm volatile("s_waitcnt vmcnt(0)" ::: "memory");  // drain stragglers

        // ---- epilogue: pair-reduce l, store O
        float lt = l_ + __shfl_xor(l_, 32);
        const bool val = (q < qlen);
        const float inv = val ? (1.0f / lt) : 0.f;
        float* op = out + (((size_t)b * QQ + q) * HH + h) * DD;
        #pragma unroll
        for (int rr = 0; rr < 4; ++rr) {
            f32x4 wv;
            const int d0 = rr * 8 + hi * 4;
            wv[0] = o0[rr*4+0]*inv; wv[1] = o0[rr*4+1]*inv;
            wv[2] = o0[rr*4+2]*inv; wv[3] = o0[rr*4+3]*inv;
            *(f32x4*)&op[d0] = wv;
            wv[0] = o1[rr*4+0]*inv; wv[1] = o1[rr*4+1]*inv;
            wv[2] = o1[rr*4+2]*inv; wv[3] = o1[rr*4+3]*inv;
            *(f32x4*)&op[32 + d0] = wv;
            wv[0] = o2[rr*4+0]*inv; wv[1] = o2[rr*4+1]*inv;
            wv[2] = o2[rr*4+2]*inv; wv[3] = o2[rr*4+3]*inv;
            *(f32x4*)&op[64 + d0] = wv;
            wv[0] = o3[rr*4+0]*inv; wv[1] = o3[rr*4+1]*inv;
            wv[2] = o3[rr*4+2]*inv; wv[3] = o3[rr*4+3]*inv;
            *(f32x4*)&op[96 + d0] = wv;
        }
    }
}

// ---------------- R1 fallback (proven) if ws too small ----------------
__global__ __launch_bounds__(256)
void segattn(const float* __restrict__ qs, const float* __restrict__ ks,
             const float* __restrict__ vs, const float* __restrict__ kc,
             const float* __restrict__ vc, const int* __restrict__ qlens,
             const int* __restrict__ clens, float* __restrict__ out)
{
    const int qt = blockIdx.x, h = blockIdx.y, b = blockIdx.z;
    const int tid = threadIdx.x, wave = tid >> 6, lane = tid & 63;
    const int g = lane >> 4, lc = lane & 15;
    const int qlen = qlens[b], clen = clens[b];
    const int q0 = qt * 64;
    if (q0 >= qlen) {
        f32x4 z = {0.f, 0.f, 0.f, 0.f};
        #pragma unroll
        for (int i2 = 0; i2 < 8; ++i2) {
            int f = tid + i2 * 256;
            int r = f >> 5, d4 = f & 31;
            *(f32x4*)&out[(((size_t)b * QQ + q0 + r) * HH + h) * DD + d4 * 4] = z;
        }
        return;
    }
    alignas(16) __shared__ unsigned short Kl[KT * DD];
    alignas(16) __shared__ unsigned short Vl[DD * 40];
    alignas(16) __shared__ unsigned short Pl[4][16][40];
    const float psc = 0.08838834764831845f * 1.4426950408889634f;
    const int qrow = q0 + wave * 16 + lc;
    const float* qp = qs + (((size_t)b * QQ + qrow) * HH + h) * DD;
    short8 qf[4];
    #pragma unroll
    for (int c = 0; c < 4; ++c) {
        f32x4 a0 = *(const f32x4*)&qp[c * 32 + g * 8];
        f32x4 a1 = *(const f32x4*)&qp[c * 32 + g * 8 + 4];
        short8 t;
        t[0] = (short)f2bf(a0[0] * psc); t[1] = (short)f2bf(a0[1] * psc);
        t[2] = (short)f2bf(a0[2] * psc); t[3] = (short)f2bf(a0[3] * psc);
        t[4] = (short)f2bf(a1[0] * psc); t[5] = (short)f2bf(a1[1] * psc);
        t[6] = (short)f2bf(a1[2] * psc); t[7] = (short)f2bf(a1[3] * psc);
        qf[c] = t;
    }
    f32x4 o[8];
    #pragma unroll
    for (int n = 0; n < 8; ++n) o[n] = (f32x4){0.f, 0.f, 0.f, 0.f};
    float m_[4] = {-3e38f, -3e38f, -3e38f, -3e38f};
    float l_[4] = {0.f, 0.f, 0.f, 0.f};
    int lim[4];
    #pragma unroll
    for (int qq = 0; qq < 4; ++qq) {
        int i = q0 + wave * 16 + g * 4 + qq;
        lim[qq] = (i < qlen) ? (clen + i + 1) : 0;
    }
    const int kmax = clen + min(q0 + 64, qlen);
    const int nt = (kmax + KT - 1) / KT;
    for (int t = 0; t < nt; ++t) {
        const int pbase = t * KT;
        __syncthreads();
        #pragma unroll
        for (int it = 0; it < 4; ++it) {
            int f = tid + it * 256;
            int key = f >> 5, d4 = f & 31;
            int p = pbase + key;
            const float *srck, *srcv;
            if (p < clen) {
                size_t off = (((size_t)b * SS + p) * HH + h) * DD + d4 * 4;
                srck = kc + off; srcv = vc + off;
            } else {
                int idx = p - clen; if (idx > QQ - 1) idx = QQ - 1;
                size_t off = (((size_t)b * QQ + idx) * HH + h) * DD + d4 * 4;
                srck = ks + off; srcv = vs + off;
            }
            f32x4 kv = *(const f32x4*)srck;
            f32x4 vv = *(const f32x4*)srcv;
            int ei = (key * DD + d4 * 4) ^ ((key & 7) << 3);
            typedef __attribute__((ext_vector_type(4))) unsigned short u16x4;
            u16x4 kb4 = {f2bf(kv[0]), f2bf(kv[1]), f2bf(kv[2]), f2bf(kv[3])};
            *(u16x4*)&Kl[ei] = kb4;
            int d0 = d4 * 4;
            Vl[(d0 + 0) * 40 + key] = f2bf(vv[0]);
            Vl[(d0 + 1) * 40 + key] = f2bf(vv[1]);
            Vl[(d0 + 2) * 40 + key] = f2bf(vv[2]);
            Vl[(d0 + 3) * 40 + key] = f2bf(vv[3]);
        }
        __syncthreads();
        f32x4 sc0 = {0.f, 0.f, 0.f, 0.f}, sc1 = {0.f, 0.f, 0.f, 0.f};
        #pragma unroll
        for (int c = 0; c < 4; ++c) {
            int i0 = (lc * DD + c * 32 + g * 8) ^ ((lc & 7) << 3);
            int i1 = ((16 + lc) * DD + c * 32 + g * 8) ^ (((16 + lc) & 7) << 3);
            short8 k0 = *(const short8*)&Kl[i0];
            short8 k1 = *(const short8*)&Kl[i1];
            sc0 = __builtin_amdgcn_mfma_f32_16x16x32_bf16(qf[c], k0, sc0, 0, 0, 0);
            sc1 = __builtin_amdgcn_mfma_f32_16x16x32_bf16(qf[c], k1, sc1, 0, 0, 0);
        }
        float pr0[4], pr1[4];
        #pragma unroll
        for (int qq = 0; qq < 4; ++qq) {
            float s0 = sc0[qq], s1 = sc1[qq];
            if (pbase + lc >= lim[qq])      s0 = -3e38f;
            if (pbase + 16 + lc >= lim[qq]) s1 = -3e38f;
            float pm = fmaxf(s0, s1);
            #pragma unroll
            for (int d2 = 1; d2 < 16; d2 <<= 1) pm = fmaxf(pm, __shfl_xor(pm, d2));
            float mn = fmaxf(m_[qq], pm);
            float alpha = exp2f(m_[qq] - mn);
            float p0 = exp2f(s0 - mn), p1 = exp2f(s1 - mn);
            float rs = p0 + p1;
            #pragma unroll
            for (int d2 = 1; d2 < 16; d2 <<= 1) rs += __shfl_xor(rs, d2);
            l_[qq] = l_[qq] * alpha + rs;
            m_[qq] = mn;
            pr0[qq] = p0; pr1[qq] = p1;
            #pragma unroll
            for (int n = 0; n < 8; ++n) o[n][qq] *= alpha;
        }
        #pragma unroll
        for (int qq = 0; qq < 4; ++qq) {
            Pl[wave][g * 4 + qq][lc]      = f2bf(pr0[qq]);
            Pl[wave][g * 4 + qq][16 + lc] = f2bf(pr1[qq]);
        }
        short8 pf = *(const short8*)&Pl[wave][lc][g * 8];
        #pragma unroll
        for (int n = 0; n < 8; ++n) {
            short8 vf = *(const short8*)&Vl[(n * 16 + lc) * 40 + g * 8];
            o[n] = __builtin_amdgcn_mfma_f32_16x16x32_bf16(pf, vf, o[n], 0, 0, 0);
        }
    }
    #pragma unroll
    for (int qq = 0; qq < 4; ++qq) {
        int i = q0 + wave * 16 + g * 4 + qq;
        bool val = (i < qlen);
        float inv = val ? (1.0f / l_[qq]) : 0.f;
        size_t ob = (((size_t)b * QQ + i) * HH + h) * DD + lc;
        #pragma unroll
        for (int n = 0; n < 8; ++n)
            out[ob + (size_t)n * 16] = val ? o[n][qq] * inv : 0.f;
    }
}

extern "C" void kernel_launch(void* const* d_in, const int* in_sizes, int n_in,
                              void* d_out, int out_size, void* d_ws, size_t ws_size,
                              hipStream_t stream) {
    const float* qs = (const float*)d_in[0];
    const float* ks = (const float*)d_in[1];
    const float* vs = (const float*)d_in[2];
    const float* kc = (const float*)d_in[3];
    const float* vc = (const float*)d_in[4];
    const int* ql = (const int*)d_in[5];
    const int* cl = (const int*)d_in[6];
    float* o = (float*)d_out;

    const size_t kv_elems = (size_t)BB * HH * NTILES * TILE_ELEMS;
    const size_t kv_bytes = kv_elems * 2 * sizeof(unsigned short);   // 128 MiB
    const size_t need = kv_bytes + 128;

    if (ws_size >= need) {
        unsigned short* Kws = (unsigned short*)d_ws;
        unsigned short* Vws = Kws + kv_elems;
        int* counter = (int*)((char*)d_ws + kv_bytes);
        hipMemsetAsync(counter, 0, 128, stream);   // 8 subqueue counters
        dim3 pgrid(NTILES, HH, BB), pblk(256, 1, 1);
        hipLaunchKernelGGL(prep, pgrid, pblk, 0, stream, ks, vs, kc, vc, ql, cl, Kws, Vws);
        dim3 grid(1024, 1, 1), blk(128, 1, 1);
        hipLaunchKernelGGL(segattn_persist, grid, blk, 0, stream, qs, ql, cl, Kws, Vws, o, counter);
    } else {
        dim3 grid(QQ / 64, HH, BB), blk(256, 1, 1);
        hipLaunchKernelGGL(segattn, grid, blk, 0, stream, qs, ks, vs, kc, vc, ql, cl, o);
    }
}

// Round 21
// 155.550 us; speedup vs baseline: 2.0091x; 2.0091x over previous
//
#include <hip/hip_runtime.h>

// FINAL (= R17, best measured: 156.5 us total / ~113 us hot, absmax 3.9e-3).
// Architecture: prep converts K/V (cache++new, ragged append resolved) to
// bf16 in 32x32-MFMA fragment order in d_ws. Hot kernel: persistent blocks,
// 8 per-XCD subqueues (L2-affine, heavy-first LPT), 2-wave/128-thr blocks,
// 32 q-rows/wave via mfma_f32_32x32x16_bf16 (swapped QK^T -> lane-local
// softmax), glds double-buffer staging (zero staging VGPRs), 2-phase
// pipelined loop: softmax(t) || glds in flight -> barrier -> merged MFMA
// phase QK(t+1)+PV(t) -> barrier -> issue glds(t+2). Defer-max (THR=8,
// log2 domain), interior-tile mask skip, lane-partial l, setprio on MFMA.

#define BB 4
#define QQ 1024
#define SS 2048
#define HH 32
#define DD 128
#define KT 32
#define NTILES 64
#define TILE_ELEMS 4096
#define NPERQ 256

typedef __attribute__((ext_vector_type(8))) short short8;
typedef __attribute__((ext_vector_type(4))) float f32x4;
typedef __attribute__((ext_vector_type(16))) float f32x16;
typedef __attribute__((ext_vector_type(4))) unsigned int u32x4;
typedef __attribute__((ext_vector_type(8))) unsigned short u16x8;

__device__ __forceinline__ unsigned short f2bf(float f) {
    unsigned int u = __builtin_bit_cast(unsigned int, f);
    u += 0x7FFFu + ((u >> 16) & 1u);
    return (unsigned short)(u >> 16);
}
__device__ __forceinline__ unsigned int cvtpk(float lo, float hi) {
    unsigned int r;
    asm("v_cvt_pk_bf16_f32 %0, %1, %2" : "=v"(r) : "v"(lo), "v"(hi));
    return r;
}
__device__ __forceinline__ void glds16(const unsigned short* g, unsigned short* l) {
    __builtin_amdgcn_global_load_lds(
        (const __attribute__((address_space(1))) unsigned int*)g,
        (__attribute__((address_space(3))) unsigned int*)l, 16, 0, 0);
}

// ---------------- prep: f32 cache/new -> bf16 32x32-fragment-ordered ws -------
__global__ __launch_bounds__(256)
void prep(const float* __restrict__ ks, const float* __restrict__ vs,
          const float* __restrict__ kc_, const float* __restrict__ vc,
          const int* __restrict__ qlens, const int* __restrict__ clens,
          unsigned short* __restrict__ Kws, unsigned short* __restrict__ Vws)
{
    const int tile = blockIdx.x, h = blockIdx.y, b = blockIdx.z;
    const int qlen = qlens[b], clen = clens[b];
    if (tile * KT >= clen + qlen) return;
    const int tid = threadIdx.x;
    unsigned short* kout = Kws + (((size_t)b * HH + h) * NTILES + tile) * TILE_ELEMS;
    unsigned short* vout = Vws + (((size_t)b * HH + h) * NTILES + tile) * TILE_ELEMS;

    #pragma unroll
    for (int h2 = 0; h2 < 2; ++h2) {
        const int idx8 = h2 * 2048 + tid * 8;
        const int c = idx8 >> 9, l = (idx8 >> 3) & 63;
        int key = tile * KT + (l & 31);
        const float* src;
        if (key < clen) {
            src = kc_ + (((size_t)b * SS + key) * HH + h) * DD;
        } else {
            int i2 = key - clen; if (i2 > QQ - 1) i2 = QQ - 1;
            src = ks + (((size_t)b * QQ + i2) * HH + h) * DD;
        }
        const int d0 = c * 16 + ((l >> 5) << 3);
        f32x4 a0 = *(const f32x4*)&src[d0];
        f32x4 a1 = *(const f32x4*)&src[d0 + 4];
        u16x8 w;
        w[0] = f2bf(a0[0]); w[1] = f2bf(a0[1]); w[2] = f2bf(a0[2]); w[3] = f2bf(a0[3]);
        w[4] = f2bf(a1[0]); w[5] = f2bf(a1[1]); w[6] = f2bf(a1[2]); w[7] = f2bf(a1[3]);
        *(u16x8*)&kout[idx8] = w;
    }
    #pragma unroll
    for (int h2 = 0; h2 < 2; ++h2) {
        const int idx8 = h2 * 2048 + tid * 8;
        const int a = idx8 >> 9, l = (idx8 >> 3) & 63;
        const int dchunk = a >> 1, kcc = a & 1;
        const int d = dchunk * 32 + (l & 31);
        const int kb = tile * KT + kcc * 16 + ((l >> 5) << 3);
        u16x8 w;
        #pragma unroll
        for (int e = 0; e < 8; ++e) {
            int key = kb + e;
            const float* src;
            if (key < clen) {
                src = vc + (((size_t)b * SS + key) * HH + h) * DD;
            } else {
                int i2 = key - clen; if (i2 > QQ - 1) i2 = QQ - 1;
                src = vs + (((size_t)b * QQ + i2) * HH + h) * DD;
            }
            w[e] = f2bf(src[d]);
        }
        *(u16x8*)&vout[idx8] = w;
    }
}

// ---- one pipelined tile step: softmax(T) -> sync -> QK(T+1)+PV(T) -> sync ->
// issue glds(T+2) into buf BC. SC = scores of tile T; SN gets tile T+1.
#define TSTEP(T, SC, SN, BC, BN)                                                \
{                                                                               \
    const int pbase = (T) * KT;                                                 \
    if (pbase + KT > lim_min) {                                                 \
        _Pragma("unroll")                                                       \
        for (int r = 0; r < 16; ++r) {                                          \
            const int kk = pbase + (r & 3) + ((r >> 2) << 3) + hi * 4;          \
            if (kk >= lim_l) SC[r] = -3e38f;                                    \
        }                                                                       \
    }                                                                           \
    float pm = fmaxf(fmaxf(fmaxf(fmaxf(SC[0], SC[1]), fmaxf(SC[2], SC[3])),     \
                           fmaxf(fmaxf(SC[4], SC[5]), fmaxf(SC[6], SC[7]))),    \
                     fmaxf(fmaxf(fmaxf(SC[8], SC[9]), fmaxf(SC[10], SC[11])),   \
                           fmaxf(fmaxf(SC[12], SC[13]), fmaxf(SC[14], SC[15])))); \
    if (__any(pm > m_ + 8.0f)) {                                                \
        pm = fmaxf(pm, __shfl_xor(pm, 32));                                     \
        const float mn = fmaxf(m_, pm);                                         \
        const float alpha = __builtin_amdgcn_exp2f(m_ - mn);                    \
        m_ = mn;                                                                \
        l_ *= alpha;                                                            \
        _Pragma("unroll")                                                       \
        for (int r = 0; r < 16; ++r) {                                          \
            o0[r] *= alpha; o1[r] *= alpha; o2[r] *= alpha; o3[r] *= alpha;     \
        }                                                                       \
    }                                                                           \
    float p[16];                                                                \
    _Pragma("unroll")                                                           \
    for (int r = 0; r < 16; ++r) p[r] = __builtin_amdgcn_exp2f(SC[r] - m_);     \
    l_ += (((p[0]+p[1])+(p[2]+p[3])) + ((p[4]+p[5])+(p[6]+p[7])))               \
        + (((p[8]+p[9])+(p[10]+p[11])) + ((p[12]+p[13])+(p[14]+p[15])));        \
    const unsigned int w0 = cvtpk(p[0],  p[1]);                                 \
    const unsigned int w1 = cvtpk(p[2],  p[3]);                                 \
    const unsigned int w2 = cvtpk(p[4],  p[5]);                                 \
    const unsigned int w3 = cvtpk(p[6],  p[7]);                                 \
    const unsigned int w4 = cvtpk(p[8],  p[9]);                                 \
    const unsigned int w5 = cvtpk(p[10], p[11]);                                \
    const unsigned int w6 = cvtpk(p[12], p[13]);                                \
    const unsigned int w7 = cvtpk(p[14], p[15]);                                \
    const unsigned int x0 = (unsigned int)__shfl_xor((int)w0, 32);              \
    const unsigned int x1 = (unsigned int)__shfl_xor((int)w1, 32);              \
    const unsigned int x2 = (unsigned int)__shfl_xor((int)w2, 32);              \
    const unsigned int x3 = (unsigned int)__shfl_xor((int)w3, 32);              \
    const unsigned int x4 = (unsigned int)__shfl_xor((int)w4, 32);              \
    const unsigned int x5 = (unsigned int)__shfl_xor((int)w5, 32);              \
    const unsigned int x6 = (unsigned int)__shfl_xor((int)w6, 32);              \
    const unsigned int x7 = (unsigned int)__shfl_xor((int)w7, 32);              \
    u32x4 pb0w, pb1w;                                                           \
    pb0w[0] = hiL ? x2 : w0;  pb0w[1] = hiL ? x3 : w1;                          \
    pb0w[2] = hiL ? w2 : x0;  pb0w[3] = hiL ? w3 : x1;                          \
    pb1w[0] = hiL ? x6 : w4;  pb1w[1] = hiL ? x7 : w5;                          \
    pb1w[2] = hiL ? w6 : x4;  pb1w[3] = hiL ? w7 : x5;                          \
    const short8 pb0 = __builtin_bit_cast(short8, pb0w);                        \
    const short8 pb1 = __builtin_bit_cast(short8, pb1w);                        \
    asm volatile("s_waitcnt vmcnt(0)" ::: "memory");                            \
    __builtin_amdgcn_s_barrier();                                               \
    __builtin_amdgcn_sched_barrier(0);                                          \
    SN = (f32x16){0.f};                                                         \
    __builtin_amdgcn_s_setprio(1);                                              \
    _Pragma("unroll")                                                           \
    for (int c = 0; c < 8; ++c) {                                               \
        short8 kf = *(const short8*)&KVl[BN][c * 512 + lane * 8];               \
        SN = __builtin_amdgcn_mfma_f32_32x32x16_bf16(kf, qf[c], SN, 0, 0, 0);   \
    }                                                                           \
    {                                                                           \
        short8 va = *(const short8*)&KVl[BC][4096 + 0 * 512 + lane * 8];        \
        short8 vb = *(const short8*)&KVl[BC][4096 + 1 * 512 + lane * 8];        \
        o0 = __builtin_amdgcn_mfma_f32_32x32x16_bf16(va, pb0, o0, 0, 0, 0);     \
        o0 = __builtin_amdgcn_mfma_f32_32x32x16_bf16(vb, pb1, o0, 0, 0, 0);     \
    }                                                                           \
    {                                                                           \
        short8 va = *(const short8*)&KVl[BC][4096 + 2 * 512 + lane * 8];        \
        short8 vb = *(const short8*)&KVl[BC][4096 + 3 * 512 + lane * 8];        \
        o1 = __builtin_amdgcn_mfma_f32_32x32x16_bf16(va, pb0, o1, 0, 0, 0);     \
        o1 = __builtin_amdgcn_mfma_f32_32x32x16_bf16(vb, pb1, o1, 0, 0, 0);     \
    }                                                                           \
    {                                                                           \
        short8 va = *(const short8*)&KVl[BC][4096 + 4 * 512 + lane * 8];        \
        short8 vb = *(const short8*)&KVl[BC][4096 + 5 * 512 + lane * 8];        \
        o2 = __builtin_amdgcn_mfma_f32_32x32x16_bf16(va, pb0, o2, 0, 0, 0);     \
        o2 = __builtin_amdgcn_mfma_f32_32x32x16_bf16(vb, pb1, o2, 0, 0, 0);     \
    }                                                                           \
    {                                                                           \
        short8 va = *(const short8*)&KVl[BC][4096 + 6 * 512 + lane * 8];        \
        short8 vb = *(const short8*)&KVl[BC][4096 + 7 * 512 + lane * 8];        \
        o3 = __builtin_amdgcn_mfma_f32_32x32x16_bf16(va, pb0, o3, 0, 0, 0);     \
        o3 = __builtin_amdgcn_mfma_f32_32x32x16_bf16(vb, pb1, o3, 0, 0, 0);     \
    }                                                                           \
    __builtin_amdgcn_s_setprio(0);                                              \
    asm volatile("s_waitcnt lgkmcnt(0)" ::: "memory");                          \
    __builtin_amdgcn_s_barrier();                                               \
    __builtin_amdgcn_sched_barrier(0);                                          \
    const int t2c = ((T) + 2 < nt) ? (T) + 2 : (nt - 1);                        \
    const unsigned short* k2p = Kb + (size_t)t2c * TILE_ELEMS;                  \
    const unsigned short* v2p = Vb + (size_t)t2c * TILE_ELEMS;                  \
    _Pragma("unroll")                                                           \
    for (int j = 0; j < 4; ++j) {                                               \
        glds16(&k2p[sbase + j * 512], &KVl[BC][lbase + j * 512]);               \
        glds16(&v2p[sbase + j * 512], &KVl[BC][4096 + lbase + j * 512]);        \
    }                                                                           \
}

// ---------------- hot: glds dbuf + per-XCD subqueues + 2-phase pipeline ------
__global__ __launch_bounds__(128, 2)
void segattn_persist(const float* __restrict__ qs, const int* __restrict__ qlens,
                     const int* __restrict__ clens,
                     const unsigned short* __restrict__ Kws,
                     const unsigned short* __restrict__ Vws,
                     float* __restrict__ out, int* __restrict__ counter)
{
    __shared__ int s_item;
    alignas(16) __shared__ unsigned short KVl[2][8192];  // per buf: K [0,4096) V [4096,8192)

    const int tid = threadIdx.x, w = tid >> 6, lane = tid & 63;
    const int q31 = lane & 31, hi = lane >> 5;
    const bool hiL = (hi != 0);
    const float psc = 0.08838834764831845f * 1.4426950408889634f;
    const int sbase = w * 2048 + lane * 8;   // per-lane global slice offset (hw)
    const int lbase = w * 2048;              // wave-uniform LDS slice base (hw)
    const int cres = blockIdx.x & 7;         // XCD residue queue
    int* myctr = counter + cres;

    for (;;) {
        if (tid == 0) s_item = atomicAdd(myctr, 1);
        __syncthreads();
        const int pop = s_item;
        __syncthreads();
        if (pop >= NPERQ) break;

        const int bhi = pop >> 4, qtord = pop & 15;
        const int qt = 15 - qtord;
        const int b = bhi & 3, h = cres + 8 * (bhi >> 2);
        const int qlen = qlens[b], clen = clens[b];
        const int q0 = qt * 64;

        if (q0 >= qlen) {                    // fully padded tile -> zeros
            f32x4 z = {0.f, 0.f, 0.f, 0.f};
            #pragma unroll
            for (int i2 = 0; i2 < 16; ++i2) {
                int f = tid + i2 * 128;
                int r = f >> 5, d4 = f & 31;
                *(f32x4*)&out[(((size_t)b * QQ + q0 + r) * HH + h) * DD + d4 * 4] = z;
            }
            continue;
        }

        const int q = q0 + w * 32 + q31;
        const float* qp = qs + (((size_t)b * QQ + q) * HH + h) * DD;
        short8 qf[8];
        #pragma unroll
        for (int c = 0; c < 8; ++c) {
            const int d0 = c * 16 + hi * 8;
            f32x4 a0 = *(const f32x4*)&qp[d0];
            f32x4 a1 = *(const f32x4*)&qp[d0 + 4];
            short8 t;
            t[0] = (short)f2bf(a0[0] * psc); t[1] = (short)f2bf(a0[1] * psc);
            t[2] = (short)f2bf(a0[2] * psc); t[3] = (short)f2bf(a0[3] * psc);
            t[4] = (short)f2bf(a1[0] * psc); t[5] = (short)f2bf(a1[1] * psc);
            t[6] = (short)f2bf(a1[2] * psc); t[7] = (short)f2bf(a1[3] * psc);
            qf[c] = t;
        }

        const int lim_l = (q < qlen) ? (clen + q + 1) : 0;
        const int wq0 = q0 + w * 32;
        const int lim_min = (wq0 + 31 < qlen) ? (clen + wq0 + 1) : 0;

        float m_ = -3e38f, l_ = 0.f;
        f32x16 o0 = {0}, o1 = {0}, o2 = {0}, o3 = {0};

        const int kmax = clen + min(q0 + 64, qlen);
        const int nt = (kmax + KT - 1) / KT;
        const unsigned short* Kb = Kws + ((size_t)(b * HH + h)) * NTILES * TILE_ELEMS;
        const unsigned short* Vb = Vws + ((size_t)(b * HH + h)) * NTILES * TILE_ELEMS;

        // ---- prologue: glds tile0 -> buf0; QK(t0); issue glds t1 -> buf1
        #pragma unroll
        for (int j = 0; j < 4; ++j) {
            glds16(&Kb[sbase + j * 512], &KVl[0][lbase + j * 512]);
            glds16(&Vb[sbase + j * 512], &KVl[0][4096 + lbase + j * 512]);
        }
        asm volatile("s_waitcnt vmcnt(0)" ::: "memory");
        __builtin_amdgcn_s_barrier();
        __builtin_amdgcn_sched_barrier(0);
        {
            const int t1x = (nt > 1) ? 1 : 0;
            const unsigned short* k1p = Kb + (size_t)t1x * TILE_ELEMS;
            const unsigned short* v1p = Vb + (size_t)t1x * TILE_ELEMS;
            #pragma unroll
            for (int j = 0; j < 4; ++j) {
                glds16(&k1p[sbase + j * 512], &KVl[1][lbase + j * 512]);
                glds16(&v1p[sbase + j * 512], &KVl[1][4096 + lbase + j * 512]);
            }
        }
        f32x16 sA = {0}, sB;
        __builtin_amdgcn_s_setprio(1);
        #pragma unroll
        for (int c = 0; c < 8; ++c) {
            short8 kf = *(const short8*)&KVl[0][c * 512 + lane * 8];
            sA = __builtin_amdgcn_mfma_f32_32x32x16_bf16(kf, qf[c], sA, 0, 0, 0);
        }
        __builtin_amdgcn_s_setprio(0);

        int t = 0;
        for (; t + 2 <= nt; t += 2) {
            TSTEP(t,     sA, sB, 0, 1);
            TSTEP(t + 1, sB, sA, 1, 0);
        }
        if (t < nt) {
            TSTEP(t, sA, sB, 0, 1);
        }
        asm volatile("s_waitcnt vmcnt(0)" ::: "memory");  // drain before reuse

        // ---- epilogue: pair-reduce l, store O
        float lt = l_ + __shfl_xor(l_, 32);
        const bool val = (q < qlen);
        const float inv = val ? (1.0f / lt) : 0.f;
        float* op = out + (((size_t)b * QQ + q) * HH + h) * DD;
        #pragma unroll
        for (int rr = 0; rr < 4; ++rr) {
            f32x4 wv;
            const int d0 = rr * 8 + hi * 4;
            wv[0] = o0[rr*4+0]*inv; wv[1] = o0[rr*4+1]*inv;
            wv[2] = o0[rr*4+2]*inv; wv[3] = o0[rr*4+3]*inv;
            *(f32x4*)&op[d0] = wv;
            wv[0] = o1[rr*4+0]*inv; wv[1] = o1[rr*4+1]*inv;
            wv[2] = o1[rr*4+2]*inv; wv[3] = o1[rr*4+3]*inv;
            *(f32x4*)&op[32 + d0] = wv;
            wv[0] = o2[rr*4+0]*inv; wv[1] = o2[rr*4+1]*inv;
            wv[2] = o2[rr*4+2]*inv; wv[3] = o2[rr*4+3]*inv;
            *(f32x4*)&op[64 + d0] = wv;
            wv[0] = o3[rr*4+0]*inv; wv[1] = o3[rr*4+1]*inv;
            wv[2] = o3[rr*4+2]*inv; wv[3] = o3[rr*4+3]*inv;
            *(f32x4*)&op[96 + d0] = wv;
        }
    }
}

// ---------------- R1 fallback (proven) if ws too small ----------------
__global__ __launch_bounds__(256)
void segattn(const float* __restrict__ qs, const float* __restrict__ ks,
             const float* __restrict__ vs, const float* __restrict__ kc,
             const float* __restrict__ vc, const int* __restrict__ qlens,
             const int* __restrict__ clens, float* __restrict__ out)
{
    const int qt = blockIdx.x, h = blockIdx.y, b = blockIdx.z;
    const int tid = threadIdx.x, wave = tid >> 6, lane = tid & 63;
    const int g = lane >> 4, lc = lane & 15;
    const int qlen = qlens[b], clen = clens[b];
    const int q0 = qt * 64;
    if (q0 >= qlen) {
        f32x4 z = {0.f, 0.f, 0.f, 0.f};
        #pragma unroll
        for (int i2 = 0; i2 < 8; ++i2) {
            int f = tid + i2 * 256;
            int r = f >> 5, d4 = f & 31;
            *(f32x4*)&out[(((size_t)b * QQ + q0 + r) * HH + h) * DD + d4 * 4] = z;
        }
        return;
    }
    alignas(16) __shared__ unsigned short Kl[KT * DD];
    alignas(16) __shared__ unsigned short Vl[DD * 40];
    alignas(16) __shared__ unsigned short Pl[4][16][40];
    const float psc = 0.08838834764831845f * 1.4426950408889634f;
    const int qrow = q0 + wave * 16 + lc;
    const float* qp = qs + (((size_t)b * QQ + qrow) * HH + h) * DD;
    short8 qf[4];
    #pragma unroll
    for (int c = 0; c < 4; ++c) {
        f32x4 a0 = *(const f32x4*)&qp[c * 32 + g * 8];
        f32x4 a1 = *(const f32x4*)&qp[c * 32 + g * 8 + 4];
        short8 t;
        t[0] = (short)f2bf(a0[0] * psc); t[1] = (short)f2bf(a0[1] * psc);
        t[2] = (short)f2bf(a0[2] * psc); t[3] = (short)f2bf(a0[3] * psc);
        t[4] = (short)f2bf(a1[0] * psc); t[5] = (short)f2bf(a1[1] * psc);
        t[6] = (short)f2bf(a1[2] * psc); t[7] = (short)f2bf(a1[3] * psc);
        qf[c] = t;
    }
    f32x4 o[8];
    #pragma unroll
    for (int n = 0; n < 8; ++n) o[n] = (f32x4){0.f, 0.f, 0.f, 0.f};
    float m_[4] = {-3e38f, -3e38f, -3e38f, -3e38f};
    float l_[4] = {0.f, 0.f, 0.f, 0.f};
    int lim[4];
    #pragma unroll
    for (int qq = 0; qq < 4; ++qq) {
        int i = q0 + wave * 16 + g * 4 + qq;
        lim[qq] = (i < qlen) ? (clen + i + 1) : 0;
    }
    const int kmax = clen + min(q0 + 64, qlen);
    const int nt = (kmax + KT - 1) / KT;
    for (int t = 0; t < nt; ++t) {
        const int pbase = t * KT;
        __syncthreads();
        #pragma unroll
        for (int it = 0; it < 4; ++it) {
            int f = tid + it * 256;
            int key = f >> 5, d4 = f & 31;
            int p = pbase + key;
            const float *srck, *srcv;
            if (p < clen) {
                size_t off = (((size_t)b * SS + p) * HH + h) * DD + d4 * 4;
                srck = kc + off; srcv = vc + off;
            } else {
                int idx = p - clen; if (idx > QQ - 1) idx = QQ - 1;
                size_t off = (((size_t)b * QQ + idx) * HH + h) * DD + d4 * 4;
                srck = ks + off; srcv = vs + off;
            }
            f32x4 kv = *(const f32x4*)srck;
            f32x4 vv = *(const f32x4*)srcv;
            int ei = (key * DD + d4 * 4) ^ ((key & 7) << 3);
            typedef __attribute__((ext_vector_type(4))) unsigned short u16x4;
            u16x4 kb4 = {f2bf(kv[0]), f2bf(kv[1]), f2bf(kv[2]), f2bf(kv[3])};
            *(u16x4*)&Kl[ei] = kb4;
            int d0 = d4 * 4;
            Vl[(d0 + 0) * 40 + key] = f2bf(vv[0]);
            Vl[(d0 + 1) * 40 + key] = f2bf(vv[1]);
            Vl[(d0 + 2) * 40 + key] = f2bf(vv[2]);
            Vl[(d0 + 3) * 40 + key] = f2bf(vv[3]);
        }
        __syncthreads();
        f32x4 sc0 = {0.f, 0.f, 0.f, 0.f}, sc1 = {0.f, 0.f, 0.f, 0.f};
        #pragma unroll
        for (int c = 0; c < 4; ++c) {
            int i0 = (lc * DD + c * 32 + g * 8) ^ ((lc & 7) << 3);
            int i1 = ((16 + lc) * DD + c * 32 + g * 8) ^ (((16 + lc) & 7) << 3);
            short8 k0 = *(const short8*)&Kl[i0];
            short8 k1 = *(const short8*)&Kl[i1];
            sc0 = __builtin_amdgcn_mfma_f32_16x16x32_bf16(qf[c], k0, sc0, 0, 0, 0);
            sc1 = __builtin_amdgcn_mfma_f32_16x16x32_bf16(qf[c], k1, sc1, 0, 0, 0);
        }
        float pr0[4], pr1[4];
        #pragma unroll
        for (int qq = 0; qq < 4; ++qq) {
            float s0 = sc0[qq], s1 = sc1[qq];
            if (pbase + lc >= lim[qq])      s0 = -3e38f;
            if (pbase + 16 + lc >= lim[qq]) s1 = -3e38f;
            float pm = fmaxf(s0, s1);
            #pragma unroll
            for (int d2 = 1; d2 < 16; d2 <<= 1) pm = fmaxf(pm, __shfl_xor(pm, d2));
            float mn = fmaxf(m_[qq], pm);
            float alpha = exp2f(m_[qq] - mn);
            float p0 = exp2f(s0 - mn), p1 = exp2f(s1 - mn);
            float rs = p0 + p1;
            #pragma unroll
            for (int d2 = 1; d2 < 16; d2 <<= 1) rs += __shfl_xor(rs, d2);
            l_[qq] = l_[qq] * alpha + rs;
            m_[qq] = mn;
            pr0[qq] = p0; pr1[qq] = p1;
            #pragma unroll
            for (int n = 0; n < 8; ++n) o[n][qq] *= alpha;
        }
        #pragma unroll
        for (int qq = 0; qq < 4; ++qq) {
            Pl[wave][g * 4 + qq][lc]      = f2bf(pr0[qq]);
            Pl[wave][g * 4 + qq][16 + lc] = f2bf(pr1[qq]);
        }
        short8 pf = *(const short8*)&Pl[wave][lc][g * 8];
        #pragma unroll
        for (int n = 0; n < 8; ++n) {
            short8 vf = *(const short8*)&Vl[(n * 16 + lc) * 40 + g * 8];
            o[n] = __builtin_amdgcn_mfma_f32_16x16x32_bf16(pf, vf, o[n], 0, 0, 0);
        }
    }
    #pragma unroll
    for (int qq = 0; qq < 4; ++qq) {
        int i = q0 + wave * 16 + g * 4 + qq;
        bool val = (i < qlen);
        float inv = val ? (1.0f / l_[qq]) : 0.f;
        size_t ob = (((size_t)b * QQ + i) * HH + h) * DD + lc;
        #pragma unroll
        for (int n = 0; n < 8; ++n)
            out[ob + (size_t)n * 16] = val ? o[n][qq] * inv : 0.f;
    }
}

extern "C" void kernel_launch(void* const* d_in, const int* in_sizes, int n_in,
                              void* d_out, int out_size, void* d_ws, size_t ws_size,
                              hipStream_t stream) {
    const float* qs = (const float*)d_in[0];
    const float* ks = (const float*)d_in[1];
    const float* vs = (const float*)d_in[2];
    const float* kc = (const float*)d_in[3];
    const float* vc = (const float*)d_in[4];
    const int* ql = (const int*)d_in[5];
    const int* cl = (const int*)d_in[6];
    float* o = (float*)d_out;

    const size_t kv_elems = (size_t)BB * HH * NTILES * TILE_ELEMS;
    const size_t kv_bytes = kv_elems * 2 * sizeof(unsigned short);   // 128 MiB
    const size_t need = kv_bytes + 128;

    if (ws_size >= need) {
        unsigned short* Kws = (unsigned short*)d_ws;
        unsigned short* Vws = Kws + kv_elems;
        int* counter = (int*)((char*)d_ws + kv_bytes);
        hipMemsetAsync(counter, 0, 128, stream);   // 8 subqueue counters
        dim3 pgrid(NTILES, HH, BB), pblk(256, 1, 1);
        hipLaunchKernelGGL(prep, pgrid, pblk, 0, stream, ks, vs, kc, vc, ql, cl, Kws, Vws);
        dim3 grid(1024, 1, 1), blk(128, 1, 1);
        hipLaunchKernelGGL(segattn_persist, grid, blk, 0, stream, qs, ql, cl, Kws, Vws, o, counter);
    } else {
        dim3 grid(QQ / 64, HH, BB), blk(256, 1, 1);
        hipLaunchKernelGGL(segattn, grid, blk, 0, stream, qs, ks, vs, kc, vc, ql, cl, o);
    }
}